// Round 2
// baseline (397.800 us; speedup 1.0000x reference)
//
#include <hip/hip_runtime.h>

// BidirectionalBoxPool, MI355X. float32 in/out (reference dtypes preserved).
// feats (N,K,2,C,PH,MW) ++ widths (N,K,2), MW derived from out_size.
// d=1 output is an exact flip of d=0 (coords(7-i, wf-1-j), wf==width>=8 for
// valid boxes) -> compute each bilinear sample once, store to both.

namespace {
constexpr int kN = 8, kK = 64, kC = 128, kH = 128, kW = 128, kPH = 8;
constexpr int kHW = kH * kW;

__global__ __launch_bounds__(256) void boxpool_kernel(
    const float* __restrict__ x,
    const float* __restrict__ boxes,
    float* __restrict__ out,
    const int MW)
{
  const int b = blockIdx.x;          // (n*kK + k)*2 + chalf
  const int nk = b >> 1;
  const int chalf = b & 1;           // which half of the channel range
  const int n = nk >> 6;             // kK == 64
  const int tid = threadIdx.x;

  // ---- box setup (block-uniform, scalar) ----
  const int bb = nk * 4;
  const float xmin = boxes[bb + 0];
  const float ymin = boxes[bb + 1];
  const float xmax = boxes[bb + 2];
  const float ymax = boxes[bb + 3];
  const bool valid = !(xmin == 0.f && ymin == 0.f && xmax == 0.f && ymax == 0.f);
  const float bw = valid ? (xmax - xmin) : 1.f;
  const float bh = valid ? (ymax - ymin) : 1.f;
  const bool wide = bw > bh;
  const float ratio = wide ? (bw / bh) : (bh / bw);
  const int width = valid ? (int)ceilf(ratio * 8.f) : 0;  // bit-matches np fp32
  const float wf = fmaxf((float)width, 2.f);
  const int wm = width < MW ? width : MW;            // mask width (index safety)

  const int points = kPH * MW;                        // per-(n,k,d,c) elements; even
  const size_t feats_sz = (size_t)kN * kK * 2 * kC * points;

  // widths output: both directions get the same width
  if (chalf == 0 && tid == 0) {
    float2 wv; wv.x = (float)width; wv.y = (float)width;
    *reinterpret_cast<float2*>(out + feats_sz + (size_t)nk * 2) = wv;
  }

  const float* __restrict__ xn = x + ((size_t)n * kC + (size_t)chalf * 64) * kHW;
  float* __restrict__ out0 = out + ((size_t)(nk * 2 + 0) * kC + (size_t)chalf * 64) * points;
  float* __restrict__ out1 = out + ((size_t)(nk * 2 + 1) * kC + (size_t)chalf * 64) * points;

  const int pairs = points >> 1;
  for (int pp = tid; pp < pairs; pp += 256) {
    int   off[8];                      // element offsets into a (H,W) plane
    float wgt[8];
    int   e1[2];

#pragma unroll
    for (int s = 0; s < 2; ++s) {
      const int p = 2 * pp + s;
      const int i = p / MW;
      const int j = p - i * MW;
      // d=1 flip position: bijection on [0,MW): valid cols reverse, dead cols fixed
      const int jp = (j < wm) ? (wm - 1 - j) : j;
      e1[s] = (kPH - 1 - i) * MW + jp;

      float w00 = 0.f, w10 = 0.f, w01 = 0.f, w11 = 0.f;
      int   o00 = 0, o10 = 0, o01 = 0, o11 = 0;
      if (j < wm) {
        const float jf = (float)j, iff = (float)i;
        float gx, gy;
        if (wide) {
          gx = (xmin + (jf * bw) / (wf - 1.f) - 64.f) / 64.f;
          gy = (ymin + (iff * bh) / 7.f - 64.f) / 64.f;
        } else {
          gx = (xmin + (iff * bw) / 7.f - 64.f) / 64.f;
          gy = (ymin + ((wf - jf) * bh) / (wf - 1.f) - 64.f) / 64.f;
        }
        // grid_sample bilinear, align_corners=False, zeros padding
        const float ix = ((gx + 1.f) * 128.f - 1.f) * 0.5f;
        const float iy = ((gy + 1.f) * 128.f - 1.f) * 0.5f;
        const float x0 = floorf(ix), y0 = floorf(iy);
        const float wx1 = ix - x0, wx0 = (x0 + 1.f) - ix;
        const float wy1 = iy - y0, wy0 = (y0 + 1.f) - iy;
        const int xi = (int)x0, yi = (int)y0;
        const bool xb0 = (xi >= 0) && (xi <= kW - 1);
        const bool xb1 = (xi + 1 >= 0) && (xi + 1 <= kW - 1);
        const bool yb0 = (yi >= 0) && (yi <= kH - 1);
        const bool yb1 = (yi + 1 >= 0) && (yi + 1 <= kH - 1);
        const int x0c = min(max(xi, 0), kW - 1);
        const int x1c = min(max(xi + 1, 0), kW - 1);
        const int y0c = min(max(yi, 0), kH - 1);
        const int y1c = min(max(yi + 1, 0), kH - 1);
        o00 = y0c * kW + x0c; o10 = y0c * kW + x1c;
        o01 = y1c * kW + x0c; o11 = y1c * kW + x1c;
        w00 = (xb0 && yb0) ? wx0 * wy0 : 0.f;
        w10 = (xb1 && yb0) ? wx1 * wy0 : 0.f;
        w01 = (xb0 && yb1) ? wx0 * wy1 : 0.f;
        w11 = (xb1 && yb1) ? wx1 * wy1 : 0.f;
      }
      off[4 * s + 0] = o00; off[4 * s + 1] = o10;
      off[4 * s + 2] = o01; off[4 * s + 3] = o11;
      wgt[4 * s + 0] = w00; wgt[4 * s + 1] = w10;
      wgt[4 * s + 2] = w01; wgt[4 * s + 3] = w11;
    }

    // ---- channel loop: 8 gathers -> 2 samples -> 4 output elems/lane ----
#pragma unroll 4
    for (int c = 0; c < 64; ++c) {
      const float* __restrict__ plc = xn + (size_t)c * kHW;  // uniform base
      const float vA = wgt[0] * plc[off[0]] + wgt[1] * plc[off[1]]
                     + wgt[2] * plc[off[2]] + wgt[3] * plc[off[3]];
      const float vB = wgt[4] * plc[off[4]] + wgt[5] * plc[off[5]]
                     + wgt[6] * plc[off[6]] + wgt[7] * plc[off[7]];
      // d=0: packed 8B store at even element offset 2*pp (8B-aligned)
      float* o0c = out0 + (size_t)c * points;
      float2 v2; v2.x = vA; v2.y = vB;
      *reinterpret_cast<float2*>(o0c + 2 * pp) = v2;
      // d=1: flipped positions (reversed-contiguous -> still line-coalesced)
      float* o1c = out1 + (size_t)c * points;
      o1c[e1[0]] = vA;
      o1c[e1[1]] = vB;
    }
  }
}
}  // namespace

extern "C" void kernel_launch(void* const* d_in, const int* in_sizes, int n_in,
                              void* d_out, int out_size, void* d_ws, size_t ws_size,
                              hipStream_t stream) {
  (void)in_sizes; (void)n_in; (void)d_ws; (void)ws_size;
  const float* x = (const float*)d_in[0];
  const float* boxes = (const float*)d_in[1];
  float* out = (float*)d_out;

  // out_size = N*K*2*C*PH*MW + N*K*2  ->  MW
  const long long widths_elems = (long long)kN * kK * 2;            // 1024
  const long long per_mw = (long long)kN * kK * 2 * kC * kPH;       // 1048576
  const int MW = (int)(((long long)out_size - widths_elems) / per_mw);

  boxpool_kernel<<<dim3(kN * kK * 2), dim3(256), 0, stream>>>(x, boxes, out, MW);
}